// Round 1
// baseline (576.401 us; speedup 1.0000x reference)
//
#include <hip/hip_runtime.h>

// ---------------------------------------------------------------------------
// CausalSelfAttention on MI355X (gfx950), bf16 MFMA pipeline.
// B=4, T=2048, C=1024, H=16, D=64.
// Stages:
//   1) cvt x -> bf16            [8192,1024]
//   2) transpose+cvt W_kqv -> [3072,1024] bf16 ; W_proj -> [1024,1024] bf16
//   3) gemm_bt: kqv = x @ W_kqv^T(t) + b  -> bf16 [8192,3072]
//   4) flash attention (causal + padding mask) -> y bf16 [8192,1024]
//   5) gemm_bt: out = y @ W_proj^T(t) + b -> fp32 d_out
// ---------------------------------------------------------------------------

typedef short bf16x8 __attribute__((ext_vector_type(8)));
typedef float floatx4 __attribute__((ext_vector_type(4)));

#define MFMA16(a, b, c) __builtin_amdgcn_mfma_f32_16x16x32_bf16(a, b, c, 0, 0, 0)

__device__ __forceinline__ short f2bf(float f) {
  union { float f; unsigned u; } c;
  c.f = f;
  unsigned r = c.u + 0x7fffu + ((c.u >> 16) & 1u);  // RNE
  return (short)(r >> 16);
}

// --------------------------- elementwise convert ---------------------------
__global__ __launch_bounds__(256) void cvt_f32_bf16(const float* __restrict__ in,
                                                    short* __restrict__ out) {
  int i = (blockIdx.x * 256 + threadIdx.x) * 4;
  float4 v = *(const float4*)&in[i];
  short4 o;
  o.x = f2bf(v.x); o.y = f2bf(v.y); o.z = f2bf(v.z); o.w = f2bf(v.w);
  *(short4*)&out[i] = o;
}

// ------------------ transpose + convert: in[K=1024][N] -> out[N][1024] -----
__global__ __launch_bounds__(256) void transpose_cvt(const float* __restrict__ in,
                                                     short* __restrict__ out, int N) {
  int idx = blockIdx.x * 256 + threadIdx.x;  // over N*1024
  int n = idx >> 10;
  int k = idx & 1023;
  out[idx] = f2bf(in[k * N + n]);  // coalesced write, strided read (L2)
}

// --------------------------- GEMM: C = A * Bt^T + bias ---------------------
// A [M,K] bf16 row-major, Bt [N,K] bf16 row-major. 64x64 tile, BK=64,
// 256 threads = 4 waves; wave w computes rows [w*16, w*16+16) x all 64 cols.
template <int OUT_BF16>
__global__ __launch_bounds__(256) void gemm_bt(const short* __restrict__ A,
                                               const short* __restrict__ Bt,
                                               const float* __restrict__ bias,
                                               void* __restrict__ Cout,
                                               int M, int N, int K) {
  __shared__ short As[64][72];  // +8 pad: 2-way bank aliasing only (free)
  __shared__ short Bs[64][72];
  const int tid = threadIdx.x;
  const int lane = tid & 63, w = tid >> 6;
  const int l15 = lane & 15, quad = lane >> 4;
  const int koff = quad * 8;
  const int m0 = blockIdx.y * 64, n0 = blockIdx.x * 64;

  floatx4 acc[4] = {};

  const int r = tid >> 3;          // 0..31
  const int c8 = (tid & 7) * 8;    // 0,8,...,56

  for (int k0 = 0; k0 < K; k0 += 64) {
    *(uint4*)&As[r][c8]      = *(const uint4*)&A[(size_t)(m0 + r) * K + k0 + c8];
    *(uint4*)&As[r + 32][c8] = *(const uint4*)&A[(size_t)(m0 + r + 32) * K + k0 + c8];
    *(uint4*)&Bs[r][c8]      = *(const uint4*)&Bt[(size_t)(n0 + r) * K + k0 + c8];
    *(uint4*)&Bs[r + 32][c8] = *(const uint4*)&Bt[(size_t)(n0 + r + 32) * K + k0 + c8];
    __syncthreads();

    const int mrow = w * 16 + l15;
#pragma unroll
    for (int s = 0; s < 2; ++s) {
      bf16x8 a = *(const bf16x8*)&As[mrow][s * 32 + koff];
#pragma unroll
      for (int n = 0; n < 4; ++n) {
        bf16x8 b = *(const bf16x8*)&Bs[n * 16 + l15][s * 32 + koff];
        acc[n] = MFMA16(a, b, acc[n]);
      }
    }
    __syncthreads();
  }

#pragma unroll
  for (int n = 0; n < 4; ++n) {
    int col = n0 + n * 16 + l15;
    float bv = bias[col];
#pragma unroll
    for (int rr = 0; rr < 4; ++rr) {
      int row = m0 + w * 16 + quad * 4 + rr;
      float v = acc[n][rr] + bv;
      if (OUT_BF16)
        ((short*)Cout)[(size_t)row * N + col] = f2bf(v);
      else
        ((float*)Cout)[(size_t)row * N + col] = v;
    }
  }
}

// ------------------------------ flash attention ----------------------------
// kqv [B*T, 3C] bf16: K at +0, Q at +C, V at +2C (reference split order k,q,v).
// Block: 64 q-rows for one (b,h); 4 waves, wave w owns q-rows [w*16, w*16+16).
__global__ __launch_bounds__(256) void attn_flash(const short* __restrict__ kqv,
                                                  const int* __restrict__ pm,
                                                  short* __restrict__ y) {
  constexpr int T = 2048, C = 1024, C3 = 3072, D = 64, H = 16;
  __shared__ short Ks[64][72];        // K tile: [key][d]
  __shared__ short Vt[64][72];        // V^T tile: [d][key]
  __shared__ short Ps[4][16][72];     // per-wave P: [q][key]

  const int tid = threadIdx.x;
  const int lane = tid & 63, w = tid >> 6;
  const int l15 = lane & 15, quad = lane >> 4;
  const int koff = quad * 8;
  const int q0 = blockIdx.x * 64;
  const int bh = blockIdx.y;
  const int b = bh >> 4, h = bh & (H - 1);
  const size_t base = (size_t)b * T * C3;

  // Q fragments in registers (A-operand layout: m=lane&15, k=quad*8+j)
  bf16x8 qf[2];
  {
    int qrow = q0 + w * 16 + l15;
    const short* qp = &kqv[base + (size_t)qrow * C3 + C + h * D];
    qf[0] = *(const bf16x8*)&qp[koff];
    qf[1] = *(const bf16x8*)&qp[32 + koff];
  }

  floatx4 Oacc[4] = {};
  float m_i[4], l_i[4];
#pragma unroll
  for (int rr = 0; rr < 4; ++rr) { m_i[rr] = -3.0e38f; l_i[rr] = 0.f; }

  const int r = tid >> 3;
  const int c8 = (tid & 7) * 8;

  for (int k0 = 0; k0 <= q0; k0 += 64) {  // causal: tile needed iff k0 <= q0
    // ---- stage K tile (natural) and V tile (transposed) ----
    {
      const short* kp = &kqv[base + (size_t)(k0 + r) * C3 + h * D];
      *(uint4*)&Ks[r][c8] = *(const uint4*)&kp[c8];
      const short* kp2 = &kqv[base + (size_t)(k0 + r + 32) * C3 + h * D];
      *(uint4*)&Ks[r + 32][c8] = *(const uint4*)&kp2[c8];

      short tmp[8];
      const short* vp = &kqv[base + (size_t)(k0 + r) * C3 + 2 * C + h * D];
      *(uint4*)tmp = *(const uint4*)&vp[c8];
#pragma unroll
      for (int j = 0; j < 8; ++j) Vt[c8 + j][r] = tmp[j];
      const short* vp2 = &kqv[base + (size_t)(k0 + r + 32) * C3 + 2 * C + h * D];
      *(uint4*)tmp = *(const uint4*)&vp2[c8];
#pragma unroll
      for (int j = 0; j < 8; ++j) Vt[c8 + j][r + 32] = tmp[j];
    }
    __syncthreads();

    // ---- S = Q K^T (B-operand: n=key=lane&15 within tile, k=d) ----
    floatx4 Sacc[4] = {};
#pragma unroll
    for (int s = 0; s < 2; ++s) {
#pragma unroll
      for (int n = 0; n < 4; ++n) {
        bf16x8 bK = *(const bf16x8*)&Ks[n * 16 + l15][s * 32 + koff];
        Sacc[n] = MFMA16(qf[s], bK, Sacc[n]);
      }
    }

    // ---- scale + causal/padding mask (C layout: col=lane&15, row=quad*4+rr)
    const float scale = 0.125f;  // 1/sqrt(64)
    float Sv[4][4];
    const int qrowbase = q0 + w * 16 + quad * 4;
#pragma unroll
    for (int n = 0; n < 4; ++n) {
      int col = k0 + n * 16 + l15;
      bool pmok = pm[b * T + col] != 0;
#pragma unroll
      for (int rr = 0; rr < 4; ++rr) {
        float sv = Sacc[n][rr] * scale;
        if (col > qrowbase + rr || !pmok) sv = -3.0e38f;
        Sv[n][rr] = sv;
      }
    }

    // ---- online softmax ----
    float alpha[4];
#pragma unroll
    for (int rr = 0; rr < 4; ++rr) {
      float mx = fmaxf(fmaxf(Sv[0][rr], Sv[1][rr]), fmaxf(Sv[2][rr], Sv[3][rr]));
#pragma unroll
      for (int d = 1; d < 16; d <<= 1) mx = fmaxf(mx, __shfl_xor(mx, d, 64));
      float mnew = fmaxf(m_i[rr], mx);
      alpha[rr] = __expf(m_i[rr] - mnew);
      float ssum = 0.f;
#pragma unroll
      for (int n = 0; n < 4; ++n) {
        float p = __expf(Sv[n][rr] - mnew);
        Sv[n][rr] = p;
        ssum += p;
      }
#pragma unroll
      for (int d = 1; d < 16; d <<= 1) ssum += __shfl_xor(ssum, d, 64);
      l_i[rr] = l_i[rr] * alpha[rr] + ssum;
      m_i[rr] = mnew;
    }

    // ---- rescale O; P -> LDS (bf16) in [q][key] layout ----
#pragma unroll
    for (int n = 0; n < 4; ++n)
#pragma unroll
      for (int rr = 0; rr < 4; ++rr) {
        Oacc[n][rr] *= alpha[rr];
        Ps[w][quad * 4 + rr][n * 16 + l15] = f2bf(Sv[n][rr]);
      }

    // ---- O += P V  (A=P from LDS; B=V via Vt so K-contiguous) ----
#pragma unroll
    for (int s = 0; s < 2; ++s) {
      bf16x8 ap = *(const bf16x8*)&Ps[w][l15][s * 32 + koff];
#pragma unroll
      for (int n = 0; n < 4; ++n) {
        bf16x8 bV = *(const bf16x8*)&Vt[n * 16 + l15][s * 32 + koff];
        Oacc[n] = MFMA16(ap, bV, Oacc[n]);
      }
    }
    __syncthreads();
  }

  // ---- epilogue: O/l -> y bf16 [B*T, C] at col h*64+d ----
  float inv_l[4];
#pragma unroll
  for (int rr = 0; rr < 4; ++rr) inv_l[rr] = 1.0f / l_i[rr];
#pragma unroll
  for (int n = 0; n < 4; ++n) {
    int dcol = n * 16 + l15;
#pragma unroll
    for (int rr = 0; rr < 4; ++rr) {
      int rowq = q0 + w * 16 + quad * 4 + rr;
      y[((size_t)(b * T + rowq)) * C + h * D + dcol] = f2bf(Oacc[n][rr] * inv_l[rr]);
    }
  }
}

// ---------------------------------------------------------------------------
extern "C" void kernel_launch(void* const* d_in, const int* in_sizes, int n_in,
                              void* d_out, int out_size, void* d_ws, size_t ws_size,
                              hipStream_t stream) {
  constexpr int B = 4, T = 2048, C = 1024, H = 16;
  constexpr int M = B * T;        // 8192
  constexpr int N1 = 3 * C;       // 3072

  const float* x      = (const float*)d_in[0];
  const float* W_kqv  = (const float*)d_in[1];
  const float* b_kqv  = (const float*)d_in[2];
  const float* W_proj = (const float*)d_in[3];
  const float* b_proj = (const float*)d_in[4];
  const int*   pmask  = (const int*)d_in[5];
  float* out = (float*)d_out;

  short* xb     = (short*)d_ws;                 // [8192,1024]
  short* Wkqvt  = xb + (size_t)M * C;           // [3072,1024]
  short* Wprojt = Wkqvt + (size_t)N1 * C;       // [1024,1024]
  short* kqv    = Wprojt + (size_t)C * C;       // [8192,3072]
  short* yb     = kqv + (size_t)M * N1;         // [8192,1024]

  cvt_f32_bf16<<<(M * C) / (256 * 4), 256, 0, stream>>>(x, xb);
  transpose_cvt<<<(N1 * C) / 256, 256, 0, stream>>>(W_kqv, Wkqvt, N1);
  transpose_cvt<<<(C * C) / 256, 256, 0, stream>>>(W_proj, Wprojt, C);

  gemm_bt<1><<<dim3(N1 / 64, M / 64), 256, 0, stream>>>(xb, Wkqvt, b_kqv, kqv, M, N1, C);

  attn_flash<<<dim3(T / 64, B * H), 256, 0, stream>>>(kqv, pmask, yb);

  gemm_bt<0><<<dim3(C / 64, M / 64), 256, 0, stream>>>(yb, Wprojt, b_proj, out, M, C, C);
}

// Round 3
// 375.945 us; speedup vs baseline: 1.5332x; 1.5332x over previous
//
#include <hip/hip_runtime.h>

// ---------------------------------------------------------------------------
// CausalSelfAttention on MI355X (gfx950), bf16 MFMA pipeline. Round 3.
// B=4, T=2048, C=1024, H=16, D=64.
//   1) cvt x -> bf16 [8192,1024]
//   2) transpose+cvt W_kqv -> [3072,1024] bf16 ; W_proj -> [1024,1024] bf16
//   3) gemm_bt128 (m97-style, global_load_lds w=16): kqv bf16 [8192,3072]
//      + EXPLICIT s_waitcnt vmcnt(0) before barrier (fixes warm-state race)
//   4) vtrans: V -> Vt_g [bh][d][t]
//   5) attn: flash, Q-tile 64, K-tile 64, paired q-blocks for load balance
//   6) gemm_bt128: out = y @ W_proj^T + b -> fp32
// ---------------------------------------------------------------------------

typedef short bf16x8 __attribute__((ext_vector_type(8)));
typedef float floatx4 __attribute__((ext_vector_type(4)));

#define MFMA16(a, b, c) __builtin_amdgcn_mfma_f32_16x16x32_bf16(a, b, c, 0, 0, 0)

#define ASYNC_COPY16(gp, lp)                                                   \
  __builtin_amdgcn_global_load_lds(                                            \
      (__attribute__((address_space(1))) void*)(gp),                           \
      (__attribute__((address_space(3))) void*)(lp), 16, 0, 0)

// Force-drain all outstanding global_load_lds before crossing a barrier.
// The compiler is *supposed* to emit vmcnt(0) before s_barrier, but round-2
// showed stale-tile reads appearing at steady-state clocks — make it explicit.
#define DRAIN_VMCNT() asm volatile("s_waitcnt vmcnt(0)" ::: "memory")

__device__ __forceinline__ short f2bf(float f) {
  union { float f; unsigned u; } c;
  c.f = f;
  unsigned r = c.u + 0x7fffu + ((c.u >> 16) & 1u);  // RNE
  return (short)(r >> 16);
}

// --------------------------- elementwise convert ---------------------------
__global__ __launch_bounds__(256) void cvt_f32_bf16(const float* __restrict__ in,
                                                    short* __restrict__ out) {
  int i = (blockIdx.x * 256 + threadIdx.x) * 4;
  float4 v = *(const float4*)&in[i];
  short4 o;
  o.x = f2bf(v.x); o.y = f2bf(v.y); o.z = f2bf(v.z); o.w = f2bf(v.w);
  *(short4*)&out[i] = o;
}

// ------------------ transpose + convert: in[K=1024][N] -> out[N][1024] -----
__global__ __launch_bounds__(256) void transpose_cvt(const float* __restrict__ in,
                                                     short* __restrict__ out, int N) {
  int idx = blockIdx.x * 256 + threadIdx.x;
  int n = idx >> 10;
  int k = idx & 1023;
  out[idx] = f2bf(in[k * N + n]);
}

// ---------------- V transpose: kqv[b,t,2C+h*64+d] -> Vt[bh][d][t] ----------
__global__ __launch_bounds__(256) void vtrans(const short* __restrict__ kqv,
                                              short* __restrict__ Vt) {
  constexpr int T = 2048, C = 1024, C3 = 3072;
  __shared__ short buf[64][72];
  const int tid = threadIdx.x;
  const int bh = blockIdx.y;
  const int b = bh >> 4, h = bh & 15;
  const int t0 = blockIdx.x * 64;
  const int r = tid >> 3, c8 = (tid & 7) * 8;

  const short* src = &kqv[(size_t)b * T * C3 + (size_t)(t0 + r) * C3 + 2 * C + h * 64 + c8];
  *(uint4*)&buf[r][c8] = *(const uint4*)src;
  *(uint4*)&buf[r + 32][c8] = *(const uint4*)(src + (size_t)32 * C3);
  __syncthreads();

  short tmp[8];
#pragma unroll
  for (int j = 0; j < 8; ++j) tmp[j] = buf[c8 + j][r];
  *(uint4*)&Vt[((size_t)bh * 64 + r) * T + t0 + c8] = *(uint4*)tmp;
#pragma unroll
  for (int j = 0; j < 8; ++j) tmp[j] = buf[c8 + j][r + 32];
  *(uint4*)&Vt[((size_t)bh * 64 + r + 32) * T + t0 + c8] = *(uint4*)tmp;
}

// ------------------- GEMM (m97-style): C = A * Bt^T + bias -----------------
// A [M,K] bf16 rm, Bt [N,K] bf16 rm. 128x128 tile, BK=64, 4 waves (2x2),
// each wave 64x64 via 4x4 of 16x16x32 MFMA. global_load_lds width 16.
template <int OUT_BF16>
__global__ __launch_bounds__(256) void gemm_bt128(const short* __restrict__ A,
                                                  const short* __restrict__ Bt,
                                                  const float* __restrict__ bias,
                                                  void* __restrict__ Cout,
                                                  int M, int N, int K) {
  __shared__ short As[128 * 64];
  __shared__ short Bs[128 * 64];
  const int tid = threadIdx.x;
  const int lane = tid & 63;
  const int wv = tid >> 6;
  const int l15 = lane & 15, quad = lane >> 4;
  const int koff = quad * 8;
  const int m0 = blockIdx.y * 128, n0 = blockIdx.x * 128;
  const int wm = (wv >> 1) * 64, wn = (wv & 1) * 64;

  floatx4 acc[4][4] = {};

  const int srow = tid >> 3;         // 0..31
  const int schunk = (tid & 7) * 8;  // 0..56

  const short* Ap = &A[(size_t)(m0 + srow) * K + schunk];
  const short* Bp = &Bt[(size_t)(n0 + srow) * K + schunk];
  short* Asp = &As[tid * 8];
  short* Bsp = &Bs[tid * 8];

  for (int k0 = 0; k0 < K; k0 += 64) {
#pragma unroll
    for (int i = 0; i < 4; ++i) {
      ASYNC_COPY16(Ap + (size_t)(i * 32) * K + k0, Asp + i * 2048);
      ASYNC_COPY16(Bp + (size_t)(i * 32) * K + k0, Bsp + i * 2048);
    }
    DRAIN_VMCNT();      // all 8 async copies landed in LDS
    __syncthreads();
#pragma unroll
    for (int s = 0; s < 2; ++s) {
      bf16x8 af[4], bfr[4];
#pragma unroll
      for (int i = 0; i < 4; ++i) {
        af[i]  = *(const bf16x8*)&As[(wm + i * 16 + l15) * 64 + s * 32 + koff];
        bfr[i] = *(const bf16x8*)&Bs[(wn + i * 16 + l15) * 64 + s * 32 + koff];
      }
#pragma unroll
      for (int mi = 0; mi < 4; ++mi)
#pragma unroll
        for (int ni = 0; ni < 4; ++ni)
          acc[mi][ni] = MFMA16(af[mi], bfr[ni], acc[mi][ni]);
    }
    __syncthreads();
  }

#pragma unroll
  for (int ni = 0; ni < 4; ++ni) {
    int col = n0 + wn + ni * 16 + l15;
    float bv = bias[col];
#pragma unroll
    for (int mi = 0; mi < 4; ++mi) {
#pragma unroll
      for (int rr = 0; rr < 4; ++rr) {
        int row = m0 + wm + mi * 16 + quad * 4 + rr;
        float v = acc[mi][ni][rr] + bv;
        if (OUT_BF16)
          ((short*)Cout)[(size_t)row * N + col] = f2bf(v);
        else
          ((float*)Cout)[(size_t)row * N + col] = v;
      }
    }
  }
}

// ------------------------------ flash attention ----------------------------
// Q-tile 64, K-tile 64, 4 waves (wave owns 16 q-rows). Each block processes
// the balanced pair of q-blocks {qb, 31-qb} -> exactly 33 k-tiles per block.
__global__ __launch_bounds__(256) void attn_flash2(const short* __restrict__ kqv,
                                                   const short* __restrict__ Vt,
                                                   const int* __restrict__ pm,
                                                   short* __restrict__ y) {
  constexpr int T = 2048, C = 1024, C3 = 3072;
  __shared__ short Ks[64][72];     // [key][d]
  __shared__ short Vs[64][72];     // [d][key]  (from pre-transposed Vt)
  __shared__ short Ps[4][16][72];  // per-wave P: [q][key]

  const int tid = threadIdx.x;
  const int lane = tid & 63, w = tid >> 6;
  const int l15 = lane & 15, quad = lane >> 4;
  const int koff = quad * 8;
  const int bh = blockIdx.y;
  const int b = bh >> 4, h = bh & 15;
  const size_t base = (size_t)b * T * C3;
  const short* Vbase = &Vt[(size_t)bh * 64 * T];

  const int srow = tid >> 3;
  const int schunk = (tid & 7) * 8;

#pragma unroll 1
  for (int half = 0; half < 2; ++half) {
    const int qb = half == 0 ? (int)blockIdx.x : 31 - (int)blockIdx.x;
    const int q0 = qb * 64;

    bf16x8 qf[2];
    {
      int qrow = q0 + w * 16 + l15;
      const short* qp = &kqv[base + (size_t)qrow * C3 + C + h * 64];
      qf[0] = *(const bf16x8*)&qp[koff];
      qf[1] = *(const bf16x8*)&qp[32 + koff];
    }

    floatx4 Oacc[4] = {};
    float m_i[4], l_i[4];
#pragma unroll
    for (int rr = 0; rr < 4; ++rr) { m_i[rr] = -3.0e38f; l_i[rr] = 0.f; }

    for (int k0 = 0; k0 <= q0; k0 += 64) {
      // ---- stage K tile and V^T tile, all uint4 ----
      {
        const short* kp = &kqv[base + (size_t)(k0 + srow) * C3 + h * 64 + schunk];
        *(uint4*)&Ks[srow][schunk] = *(const uint4*)kp;
        *(uint4*)&Ks[srow + 32][schunk] = *(const uint4*)(kp + (size_t)32 * C3);
        const short* vp = &Vbase[(size_t)srow * T + k0 + schunk];
        *(uint4*)&Vs[srow][schunk] = *(const uint4*)vp;
        *(uint4*)&Vs[srow + 32][schunk] = *(const uint4*)(vp + (size_t)32 * T);
      }
      __syncthreads();

      // ---- S = Q K^T ----
      floatx4 Sacc[4] = {};
#pragma unroll
      for (int s = 0; s < 2; ++s) {
#pragma unroll
        for (int n = 0; n < 4; ++n) {
          bf16x8 bK = *(const bf16x8*)&Ks[n * 16 + l15][s * 32 + koff];
          Sacc[n] = MFMA16(qf[s], bK, Sacc[n]);
        }
      }

      // ---- scale + causal/padding mask ----
      const float scale = 0.125f;
      float Sv[4][4];
      const int qrowbase = q0 + w * 16 + quad * 4;
#pragma unroll
      for (int n = 0; n < 4; ++n) {
        int col = k0 + n * 16 + l15;
        bool pmok = pm[b * T + col] != 0;
#pragma unroll
        for (int rr = 0; rr < 4; ++rr) {
          float sv = Sacc[n][rr] * scale;
          if (col > qrowbase + rr || !pmok) sv = -3.0e38f;
          Sv[n][rr] = sv;
        }
      }

      // ---- online softmax (rows span 16 lanes: 4-round butterflies) ----
      float alpha[4];
#pragma unroll
      for (int rr = 0; rr < 4; ++rr) {
        float mx = fmaxf(fmaxf(Sv[0][rr], Sv[1][rr]), fmaxf(Sv[2][rr], Sv[3][rr]));
#pragma unroll
        for (int d = 1; d < 16; d <<= 1) mx = fmaxf(mx, __shfl_xor(mx, d, 64));
        float mnew = fmaxf(m_i[rr], mx);
        alpha[rr] = __expf(m_i[rr] - mnew);
        float ssum = 0.f;
#pragma unroll
        for (int n = 0; n < 4; ++n) {
          float p = __expf(Sv[n][rr] - mnew);
          Sv[n][rr] = p;
          ssum += p;
        }
#pragma unroll
        for (int d = 1; d < 16; d <<= 1) ssum += __shfl_xor(ssum, d, 64);
        l_i[rr] = l_i[rr] * alpha[rr] + ssum;
        m_i[rr] = mnew;
      }

      // ---- rescale O; P -> LDS in A-operand-ready layout ----
#pragma unroll
      for (int n = 0; n < 4; ++n)
#pragma unroll
        for (int rr = 0; rr < 4; ++rr) {
          Oacc[n][rr] *= alpha[rr];
          Ps[w][quad * 4 + rr][n * 16 + l15] = f2bf(Sv[n][rr]);
        }

      // ---- O += P V ----
#pragma unroll
      for (int s = 0; s < 2; ++s) {
        bf16x8 ap = *(const bf16x8*)&Ps[w][l15][s * 32 + koff];
#pragma unroll
        for (int n = 0; n < 4; ++n) {
          bf16x8 bV = *(const bf16x8*)&Vs[n * 16 + l15][s * 32 + koff];
          Oacc[n] = MFMA16(ap, bV, Oacc[n]);
        }
      }
      __syncthreads();
    }

    // ---- epilogue ----
    float inv_l[4];
#pragma unroll
    for (int rr = 0; rr < 4; ++rr) inv_l[rr] = 1.0f / l_i[rr];
#pragma unroll
    for (int n = 0; n < 4; ++n) {
      int dcol = n * 16 + l15;
#pragma unroll
      for (int rr = 0; rr < 4; ++rr) {
        int rowq = q0 + w * 16 + quad * 4 + rr;
        y[((size_t)(b * T + rowq)) * C + h * 64 + dcol] = f2bf(Oacc[n][rr] * inv_l[rr]);
      }
    }
  }
}

// ---------------------------------------------------------------------------
extern "C" void kernel_launch(void* const* d_in, const int* in_sizes, int n_in,
                              void* d_out, int out_size, void* d_ws, size_t ws_size,
                              hipStream_t stream) {
  constexpr int B = 4, T = 2048, C = 1024;
  constexpr int M = B * T;   // 8192
  constexpr int N1 = 3 * C;  // 3072

  const float* x      = (const float*)d_in[0];
  const float* W_kqv  = (const float*)d_in[1];
  const float* b_kqv  = (const float*)d_in[2];
  const float* W_proj = (const float*)d_in[3];
  const float* b_proj = (const float*)d_in[4];
  const int*   pmask  = (const int*)d_in[5];
  float* out = (float*)d_out;

  short* xb     = (short*)d_ws;                 // [8192,1024] (reused for y)
  short* Wkqvt  = xb + (size_t)M * C;           // [3072,1024]
  short* Wprojt = Wkqvt + (size_t)N1 * C;       // [1024,1024]
  short* kqv    = Wprojt + (size_t)C * C;       // [8192,3072]
  short* Vt_g   = kqv + (size_t)M * N1;         // [64][64][2048]
  short* yb     = xb;                           // alias: x dead after gemm1

  cvt_f32_bf16<<<(M * C) / (256 * 4), 256, 0, stream>>>(x, xb);
  transpose_cvt<<<(N1 * C) / 256, 256, 0, stream>>>(W_kqv, Wkqvt, N1);
  transpose_cvt<<<(C * C) / 256, 256, 0, stream>>>(W_proj, Wprojt, C);

  gemm_bt128<1><<<dim3(N1 / 128, M / 128), 256, 0, stream>>>(xb, Wkqvt, b_kqv, kqv, M, N1, C);

  vtrans<<<dim3(T / 64, B * 16), 256, 0, stream>>>(kqv, Vt_g);

  attn_flash2<<<dim3(16, B * 16), 256, 0, stream>>>(kqv, Vt_g, pmask, yb);

  gemm_bt128<0><<<dim3(C / 128, M / 128), 256, 0, stream>>>(yb, Wprojt, b_proj, out, M, C, C);
}